// Round 13
// baseline (20.055 us; speedup 1.0000x reference)
//
#include <hip/hip_runtime.h>
#include <math.h>

// Problem constants
#define B_  32
#define D_  64
#define L_  4096
#define E_  8
#define OC_ 32
#define LP_ 4094   // L - 2 (VALID conv, kernel 3)

typedef __attribute__((ext_vector_type(8)))  short short8;
typedef __attribute__((ext_vector_type(16))) float float16;

static __device__ __forceinline__ unsigned cvtpk(float a, float b) {
    unsigned r;
    asm("v_cvt_pk_bf16_f32 %0, %1, %2" : "=v"(r) : "v"(a), "v"(b));
    return r;
}
static __device__ __forceinline__ float fast_tanh(float x) {
    float e = __expf(2.0f * x);
    return fmaf(-2.0f, __builtin_amdgcn_rcpf(e + 1.0f), 1.0f);
}

// ---------------------------------------------------------------------------
// SINGLE kernel, HIGH-TLP variant. Grid 1024 blocks (4/CU) x 256 threads
// (4 waves). Block = (batch b = blk>>5, one 128-col tile). ONE barrier.
// 4 independent blocks per CU = 4 waves/SIMD + 4 barrier domains: one
// block's load-stall overlaps another's compute/store phase.
// Prep per block (cheap, latency-overlapped): wave0-only gates + conv2
// Weff fragments (broadcast via LDS); c1w staged cooperatively (coalesced
// 24-float reads -> 3x b128 LDS writes in MFMA fragment order).
// ---------------------------------------------------------------------------
__global__ __launch_bounds__(256, 4)
void fused_all(const float* __restrict__ x,
               const float* __restrict__ w_gate,  // [320][8]
               const float* __restrict__ c1w,     // [32][64][3]
               const float* __restrict__ c1b,     // [32]
               const float* __restrict__ c2w,     // [256][32]
               const float* __restrict__ c2b,     // [256]
               float* __restrict__ out)           // [B][32][4094]
{
    // xT: bf16 [132 rows(l)][64 c], pitch 128 B, XOR-swizzle (row&7)<<4
    __shared__ __align__(16) unsigned short xT[132 * 64];     // 16896 B
    __shared__ __align__(16) unsigned short aFl[12 * 64 * 8]; // 12288 B
    __shared__ __align__(16) unsigned short a2L[2 * 64 * 8];  //  2048 B
    __shared__ float gF[2];
    __shared__ int   gI[2];

    const int tid  = threadIdx.x;
    const int lane = tid & 63;
    const int wv   = tid >> 6;              // 0..3
    const int b    = blockIdx.x >> 5;
    const int l0   = (blockIdx.x & 31) << 7;
    const float* xb = x + (size_t)b * (D_ * L_);

    // ---- issue x-tile loads (coalesced float4, c-pair rows) ----
    const int c2 = tid >> 3;                // 0..31 channel pair
    const int jb = (tid & 7) << 2;          // 0..28
    const float* p0 = xb + (size_t)(2 * c2) * L_ + l0;
    const float* p1 = p0 + L_;
    float4 A0[4], A1[4];
    #pragma unroll
    for (int jq = 0; jq < 4; ++jq) {
        int j = jq * 32 + jb;
        A0[jq] = *(const float4*)(p0 + j);
        A1[jq] = *(const float4*)(p1 + j);
    }
    float hA0 = 0.f, hA1 = 0.f;
    const int haloc = tid >> 1, haloj = tid & 1;
    if (tid < 64) {
        int lg = l0 + 128 + haloj;
        if (lg < L_) {
            hA0 = xb[(size_t)(2 * haloc) * L_ + lg];
            hA1 = xb[(size_t)(2 * haloc + 1) * L_ + lg];
        }
    }

    // ---- issue c1w loads (24 consecutive floats / thread, coalesced) ----
    const int w_oc = tid >> 3;              // 0..31
    const int w_c0 = (tid & 7) << 3;        // 0,8,..,56
    float wv24[24];
    {
        const float* wp = c1w + w_oc * 192 + w_c0 * 3;
        #pragma unroll
        for (int q = 0; q < 6; ++q)
            *(float4*)(wv24 + 4 * q) = *(const float4*)(wp + 4 * q);
    }

    // ---- WAVE 0 ONLY: gates + conv2 Weff fragments -> LDS broadcast ----
    if (wv == 0) {
        const int d = lane;
        float part[E_];
        #pragma unroll
        for (int e = 0; e < E_; ++e) part[e] = 0.f;
        #pragma unroll
        for (int t = 0; t < 5; ++t) {
            float xvt = xb[(size_t)d * L_ + (L_ - 6) + t];
            const float* wgp = w_gate + (d * 5 + t) * E_;
            float4 wa = *(const float4*)wgp;
            float4 wb = *(const float4*)(wgp + 4);
            part[0] = fmaf(xvt, wa.x, part[0]);
            part[1] = fmaf(xvt, wa.y, part[1]);
            part[2] = fmaf(xvt, wa.z, part[2]);
            part[3] = fmaf(xvt, wa.w, part[3]);
            part[4] = fmaf(xvt, wb.x, part[4]);
            part[5] = fmaf(xvt, wb.y, part[5]);
            part[6] = fmaf(xvt, wb.z, part[6]);
            part[7] = fmaf(xvt, wb.w, part[7]);
        }
        #pragma unroll
        for (int off = 1; off < 64; off <<= 1) {
            #pragma unroll
            for (int e = 0; e < E_; ++e)
                part[e] += __shfl_xor(part[e], off, 64);
        }
        float m = part[0];
        #pragma unroll
        for (int e = 1; e < E_; ++e) m = fmaxf(m, part[e]);
        float p[E_], s = 0.f;
        #pragma unroll
        for (int e = 0; e < E_; ++e) { p[e] = expf(part[e] - m); s += p[e]; }
        float inv = 1.f / s;
        #pragma unroll
        for (int e = 0; e < E_; ++e) p[e] *= inv;

        int i0 = 0;
        #pragma unroll
        for (int e = 1; e < E_; ++e) if (p[e] > p[i0]) i0 = e;
        int i1 = (i0 == 0) ? 1 : 0;
        #pragma unroll
        for (int e = 0; e < E_; ++e) {
            if (e == i0) continue;
            if (p[e] > p[i1]) i1 = e;
        }
        const float v0 = p[i0], v1 = p[i1];
        const float den = v0 + v1 + 1e-6f;
        const float g0 = v0 / den, g1 = v1 / den;

        const int cl0 = lane & 31;
        const int hi0 = lane >> 5;
        #pragma unroll
        for (int ks = 0; ks < 2; ++ks) {
            const float* q0 = c2w + (cl0 * E_ + i0) * OC_ + ks * 16 + hi0 * 8;
            const float* q1 = c2w + (cl0 * E_ + i1) * OC_ + ks * 16 + hi0 * 8;
            float4 u0a = *(const float4*)q0, u0b = *(const float4*)(q0 + 4);
            float4 u1a = *(const float4*)q1, u1b = *(const float4*)(q1 + 4);
            union { short8 s8; unsigned u[4]; } f;
            f.u[0] = cvtpk(fmaf(g0, u0a.x, g1 * u1a.x), fmaf(g0, u0a.y, g1 * u1a.y));
            f.u[1] = cvtpk(fmaf(g0, u0a.z, g1 * u1a.z), fmaf(g0, u0a.w, g1 * u1a.w));
            f.u[2] = cvtpk(fmaf(g0, u0b.x, g1 * u1b.x), fmaf(g0, u0b.y, g1 * u1b.y));
            f.u[3] = cvtpk(fmaf(g0, u0b.z, g1 * u1b.z), fmaf(g0, u0b.w, g1 * u1b.w));
            *(short8*)(a2L + (ks * 64 + lane) * 8) = f.s8;
        }
        if (lane == 0) {
            gF[0] = g0; gF[1] = g1;
            gI[0] = i0; gI[1] = i1;
        }
    }

    // ---- write c1w -> aFl in MFMA A-fragment order (3x b128 per thread) ----
    // slot for (oc,c,t): kp = t*64+c; with c0%8==0 the 8 c's fill one slot:
    // base = ((t*4 + (c0>>4))*64 + ((c0>>3)&1)*32 + oc)*8
    {
        const int ksoff = w_c0 >> 4;
        const int half  = (w_c0 >> 3) & 1;
        #pragma unroll
        for (int t = 0; t < 3; ++t) {
            union { short8 s8; unsigned u[4]; } w8;
            #pragma unroll
            for (int jj = 0; jj < 4; ++jj)
                w8.u[jj] = cvtpk(wv24[(2 * jj) * 3 + t], wv24[(2 * jj + 1) * 3 + t]);
            int base = ((t * 4 + ksoff) * 64 + half * 32 + w_oc) * 8;
            *(short8*)(aFl + base) = w8.s8;
        }
    }

    // ---- write x tile -> xT (waits tile vmcnt) ----
    #pragma unroll
    for (int jq = 0; jq < 4; ++jq) {
        float e0[4] = {A0[jq].x, A0[jq].y, A0[jq].z, A0[jq].w};
        float e1[4] = {A1[jq].x, A1[jq].y, A1[jq].z, A1[jq].w};
        #pragma unroll
        for (int r = 0; r < 4; ++r) {
            int row = jq * 32 + jb + r;
            int off = (row * 128 + c2 * 4) ^ ((row & 7) << 4);
            *(unsigned*)((char*)xT + off) = cvtpk(e0[r], e1[r]);
        }
    }
    if (tid < 64) {
        int row = 128 + haloj;
        int off = (row * 128 + haloc * 4) ^ ((row & 7) << 4);
        *(unsigned*)((char*)xT + off) = cvtpk(hA0, hA1);
    }

    __syncthreads();

    // ---- read broadcast prep results ----
    const int cl = lane & 31;
    const int hi = lane >> 5;
    short8 a1[12];
    #pragma unroll
    for (int ks = 0; ks < 12; ++ks)
        a1[ks] = *(const short8*)(aFl + (ks * 64 + lane) * 8);
    short8 a2[2];
    a2[0] = *(const short8*)(a2L + (0 * 64 + lane) * 8);
    a2[1] = *(const short8*)(a2L + (1 * 64 + lane) * 8);
    const float g0 = gF[0], g1 = gF[1];
    const int   i0 = gI[0], i1 = gI[1];

    // ---- conv1: 12 x mfma_32x32x16_bf16 ----
    const int cb = wv * 32;
    float16 acc = (float16)0.0f;
    #pragma unroll
    for (int t = 0; t < 3; ++t) {
        int row = cb + cl + t;
        int rb  = row * 128;
        int swz = (row & 7) << 4;
        #pragma unroll
        for (int q = 0; q < 4; ++q) {
            int off = (rb + q * 32 + hi * 16) ^ swz;
            short8 bf = *(const short8*)((const char*)xT + off);
            acc = __builtin_amdgcn_mfma_f32_32x32x16_bf16(a1[t * 4 + q], bf, acc, 0, 0, 0);
        }
    }

    // ---- bias + fast tanh ----
    float th[16];
    #pragma unroll
    for (int r = 0; r < 16; ++r) {
        int row = (r & 3) + 8 * (r >> 2) + 4 * hi;
        th[r] = fast_tanh(acc[r] + c1b[row]);
    }

    // ---- conv2 B-frags in-register via half-wave swap (lane ^ 32) ----
    unsigned x0a = hi ? cvtpk(th[0],  th[1])  : cvtpk(th[4],  th[5]);
    unsigned x0b = hi ? cvtpk(th[2],  th[3])  : cvtpk(th[6],  th[7]);
    unsigned x1a = hi ? cvtpk(th[8],  th[9])  : cvtpk(th[12], th[13]);
    unsigned x1b = hi ? cvtpk(th[10], th[11]) : cvtpk(th[14], th[15]);
    unsigned r0a = (unsigned)__shfl_xor((int)x0a, 32, 64);
    unsigned r0b = (unsigned)__shfl_xor((int)x0b, 32, 64);
    unsigned r1a = (unsigned)__shfl_xor((int)x1a, 32, 64);
    unsigned r1b = (unsigned)__shfl_xor((int)x1b, 32, 64);

    union U { short8 s8; unsigned u[4]; };
    U b0, b1;
    b0.u[0] = hi ? r0a : cvtpk(th[0], th[1]);
    b0.u[1] = hi ? r0b : cvtpk(th[2], th[3]);
    b0.u[2] = hi ? cvtpk(th[4], th[5]) : r0a;
    b0.u[3] = hi ? cvtpk(th[6], th[7]) : r0b;
    b1.u[0] = hi ? r1a : cvtpk(th[8], th[9]);
    b1.u[1] = hi ? r1b : cvtpk(th[10], th[11]);
    b1.u[2] = hi ? cvtpk(th[12], th[13]) : r1a;
    b1.u[3] = hi ? cvtpk(th[14], th[15]) : r1b;

    float16 acc2 = (float16)0.0f;
    acc2 = __builtin_amdgcn_mfma_f32_32x32x16_bf16(a2[0], b0.s8, acc2, 0, 0, 0);
    acc2 = __builtin_amdgcn_mfma_f32_32x32x16_bf16(a2[1], b1.s8, acc2, 0, 0, 0);

    // ---- direct stores; bias2 from L1-hot c2b ----
    int l = l0 + cb + cl;
    if (l < LP_) {
        float* ob = out + (size_t)b * (OC_ * (size_t)LP_) + l;
        #pragma unroll
        for (int r = 0; r < 16; ++r) {
            int row = (r & 3) + 8 * (r >> 2) + 4 * hi;
            float bb = fmaf(g0, c2b[row * E_ + i0], g1 * c2b[row * E_ + i1]);
            ob[(size_t)row * LP_] = acc2[r] + bb;
        }
    }
}

// ---------------------------------------------------------------------------
extern "C" void kernel_launch(void* const* d_in, const int* in_sizes, int n_in,
                              void* d_out, int out_size, void* d_ws, size_t ws_size,
                              hipStream_t stream)
{
    const float* x      = (const float*)d_in[0];
    const float* w_gate = (const float*)d_in[1];
    const float* c1w    = (const float*)d_in[2];
    const float* c1b    = (const float*)d_in[3];
    const float* c2w    = (const float*)d_in[4];
    const float* c2b    = (const float*)d_in[5];
    float* out = (float*)d_out;

    fused_all<<<B_ * 32, 256, 0, stream>>>(x, w_gate, c1w, c1b, c2w, c2b, out);
}

// Round 14
// 19.464 us; speedup vs baseline: 1.0303x; 1.0303x over previous
//
#include <hip/hip_runtime.h>
#include <math.h>

// Problem constants
#define B_  32
#define D_  64
#define L_  4096
#define E_  8
#define OC_ 32
#define LP_ 4094   // L - 2 (VALID conv, kernel 3)

typedef __attribute__((ext_vector_type(8)))  short short8;
typedef __attribute__((ext_vector_type(16))) float float16;

static __device__ __forceinline__ unsigned cvtpk(float a, float b) {
    unsigned r;
    asm("v_cvt_pk_bf16_f32 %0, %1, %2" : "=v"(r) : "v"(a), "v"(b));
    return r;
}
static __device__ __forceinline__ float fast_tanh(float x) {
    float e = __expf(2.0f * x);
    return fmaf(-2.0f, __builtin_amdgcn_rcpf(e + 1.0f), 1.0f);
}

// ---------------------------------------------------------------------------
// SINGLE kernel, SINGLE barrier, max-MLP schedule.
// Grid 256 blocks (1/CU) x 512 threads (8 waves); block = (batch, 512-col
// strip = 2 tiles of 256).
// Schedule: issue ALL loads (tile0+tile1+halos; c1w on waves 4-7; gates on
// wave 0) -> convert/write both LDS buffers -> ONE barrier -> compute tile0,
// compute tile1 (xT read-only after barrier; no further syncs).
// ---------------------------------------------------------------------------
static __device__ __forceinline__ void compute_tile(
    const unsigned short* __restrict__ xbuf,
    const short8* a1, const short8* a2,
    const float* __restrict__ c1b,
    const float* __restrict__ c2b,
    int i0, int i1, float g0, float g1,
    float* __restrict__ outb,
    int l0, int wv, int cl, int hi)
{
    const int cb = wv * 32;
    float16 acc = (float16)0.0f;
    #pragma unroll
    for (int t = 0; t < 3; ++t) {
        int row = cb + cl + t;
        int rb  = row * 128;
        int swz = (row & 7) << 4;
        #pragma unroll
        for (int q = 0; q < 4; ++q) {
            int off = (rb + q * 32 + hi * 16) ^ swz;
            short8 bf = *(const short8*)((const char*)xbuf + off);
            acc = __builtin_amdgcn_mfma_f32_32x32x16_bf16(a1[t * 4 + q], bf, acc, 0, 0, 0);
        }
    }

    float th[16];
    #pragma unroll
    for (int r = 0; r < 16; ++r) {
        int row = (r & 3) + 8 * (r >> 2) + 4 * hi;
        th[r] = fast_tanh(acc[r] + c1b[row]);
    }

    unsigned x0a = hi ? cvtpk(th[0],  th[1])  : cvtpk(th[4],  th[5]);
    unsigned x0b = hi ? cvtpk(th[2],  th[3])  : cvtpk(th[6],  th[7]);
    unsigned x1a = hi ? cvtpk(th[8],  th[9])  : cvtpk(th[12], th[13]);
    unsigned x1b = hi ? cvtpk(th[10], th[11]) : cvtpk(th[14], th[15]);
    unsigned r0a = (unsigned)__shfl_xor((int)x0a, 32, 64);
    unsigned r0b = (unsigned)__shfl_xor((int)x0b, 32, 64);
    unsigned r1a = (unsigned)__shfl_xor((int)x1a, 32, 64);
    unsigned r1b = (unsigned)__shfl_xor((int)x1b, 32, 64);

    union U { short8 s8; unsigned u[4]; };
    U b0, b1;
    b0.u[0] = hi ? r0a : cvtpk(th[0], th[1]);
    b0.u[1] = hi ? r0b : cvtpk(th[2], th[3]);
    b0.u[2] = hi ? cvtpk(th[4], th[5]) : r0a;
    b0.u[3] = hi ? cvtpk(th[6], th[7]) : r0b;
    b1.u[0] = hi ? r1a : cvtpk(th[8], th[9]);
    b1.u[1] = hi ? r1b : cvtpk(th[10], th[11]);
    b1.u[2] = hi ? cvtpk(th[12], th[13]) : r1a;
    b1.u[3] = hi ? cvtpk(th[14], th[15]) : r1b;

    float16 acc2 = (float16)0.0f;
    acc2 = __builtin_amdgcn_mfma_f32_32x32x16_bf16(a2[0], b0.s8, acc2, 0, 0, 0);
    acc2 = __builtin_amdgcn_mfma_f32_32x32x16_bf16(a2[1], b1.s8, acc2, 0, 0, 0);

    int l = l0 + cb + cl;
    if (l < LP_) {
        float* ob = outb + l;
        #pragma unroll
        for (int r = 0; r < 16; ++r) {
            int row = (r & 3) + 8 * (r >> 2) + 4 * hi;
            float bb = fmaf(g0, c2b[row * E_ + i0], g1 * c2b[row * E_ + i1]);
            ob[(size_t)row * LP_] = acc2[r] + bb;
        }
    }
}

__global__ __launch_bounds__(512, 1)
void fused_all(const float* __restrict__ x,
               const float* __restrict__ w_gate,  // [320][8]
               const float* __restrict__ c1w,     // [32][64][3]
               const float* __restrict__ c1b,     // [32]
               const float* __restrict__ c2w,     // [256][32]
               const float* __restrict__ c2b,     // [256]
               float* __restrict__ out)           // [B][32][4094]
{
    __shared__ __align__(16) unsigned short xT0[260 * 64];    // 33280 B
    __shared__ __align__(16) unsigned short xT1[260 * 64];    // 33280 B
    __shared__ __align__(16) unsigned short aFl[12 * 64 * 8]; // 12288 B
    __shared__ __align__(16) unsigned short a2L[2 * 64 * 8];  //  2048 B
    __shared__ float gF[2];
    __shared__ int   gI[2];

    const int tid  = threadIdx.x;
    const int lane = tid & 63;
    const int wv   = tid >> 6;              // 0..7
    const int b    = blockIdx.x >> 3;
    const int S    = (blockIdx.x & 7) << 9; // strip base 0..3584
    const float* xb = x + (size_t)b * (D_ * L_);

    // staging mapping: c2 = channel pair 0..31, jb = col offset
    const int c2 = tid >> 4;                // 0..31
    const int jb = (tid & 15) << 2;         // 0..60
    const float* p0 = xb + (size_t)(2 * c2) * L_;
    const float* p1 = p0 + L_;
    const int haloc = tid >> 1;
    const int haloj = tid & 1;

    // ---- issue ALL x loads: tile0 + tile1 (+ halos) ----
    float4 A0[4], A1[4], B0[4], B1[4];
    #pragma unroll
    for (int jq = 0; jq < 4; ++jq) {
        int j = S + jq * 64 + jb;
        A0[jq] = *(const float4*)(p0 + j);
        A1[jq] = *(const float4*)(p1 + j);
        B0[jq] = *(const float4*)(p0 + 256 + j);
        B1[jq] = *(const float4*)(p1 + 256 + j);
    }
    float hA0 = 0.f, hA1 = 0.f, hB0 = 0.f, hB1 = 0.f;
    if (tid < 64) {
        int lgA = S + 256 + haloj;          // <= 3841 < 4096
        hA0 = xb[(size_t)(2 * haloc) * L_ + lgA];
        hA1 = xb[(size_t)(2 * haloc + 1) * L_ + lgA];
        int lgB = S + 512 + haloj;
        if (lgB > L_ - 1) lgB = L_ - 1;     // dead-output halo on last strip
        hB0 = xb[(size_t)(2 * haloc) * L_ + lgB];
        hB1 = xb[(size_t)(2 * haloc + 1) * L_ + lgB];
    }

    // ---- waves 4-7: issue c1w loads (24 consecutive floats / thread) ----
    const int tid2 = tid - 256;
    const int w_oc = tid2 >> 3;             // 0..31
    const int w_c0 = (tid2 & 7) << 3;       // 0,8,..,56
    float wv24[24];
    if (tid >= 256) {
        const float* wp = c1w + w_oc * 192 + w_c0 * 3;
        #pragma unroll
        for (int q = 0; q < 6; ++q)
            *(float4*)(wv24 + 4 * q) = *(const float4*)(wp + 4 * q);
    }

    // ---- WAVE 0: gates + conv2 Weff fragments -> LDS broadcast ----
    if (wv == 0) {
        const int d = lane;
        float part[E_];
        #pragma unroll
        for (int e = 0; e < E_; ++e) part[e] = 0.f;
        #pragma unroll
        for (int t = 0; t < 5; ++t) {
            float xvt = xb[(size_t)d * L_ + (L_ - 6) + t];
            const float* wgp = w_gate + (d * 5 + t) * E_;
            float4 wa = *(const float4*)wgp;
            float4 wb = *(const float4*)(wgp + 4);
            part[0] = fmaf(xvt, wa.x, part[0]);
            part[1] = fmaf(xvt, wa.y, part[1]);
            part[2] = fmaf(xvt, wa.z, part[2]);
            part[3] = fmaf(xvt, wa.w, part[3]);
            part[4] = fmaf(xvt, wb.x, part[4]);
            part[5] = fmaf(xvt, wb.y, part[5]);
            part[6] = fmaf(xvt, wb.z, part[6]);
            part[7] = fmaf(xvt, wb.w, part[7]);
        }
        #pragma unroll
        for (int off = 1; off < 64; off <<= 1) {
            #pragma unroll
            for (int e = 0; e < E_; ++e)
                part[e] += __shfl_xor(part[e], off, 64);
        }
        float m = part[0];
        #pragma unroll
        for (int e = 1; e < E_; ++e) m = fmaxf(m, part[e]);
        float p[E_], s = 0.f;
        #pragma unroll
        for (int e = 0; e < E_; ++e) { p[e] = expf(part[e] - m); s += p[e]; }
        float inv = 1.f / s;
        #pragma unroll
        for (int e = 0; e < E_; ++e) p[e] *= inv;

        int i0 = 0;
        #pragma unroll
        for (int e = 1; e < E_; ++e) if (p[e] > p[i0]) i0 = e;
        int i1 = (i0 == 0) ? 1 : 0;
        #pragma unroll
        for (int e = 0; e < E_; ++e) {
            if (e == i0) continue;
            if (p[e] > p[i1]) i1 = e;
        }
        const float v0 = p[i0], v1 = p[i1];
        const float den = v0 + v1 + 1e-6f;
        const float g0 = v0 / den, g1 = v1 / den;

        const int cl0 = lane & 31;
        const int hi0 = lane >> 5;
        #pragma unroll
        for (int ks = 0; ks < 2; ++ks) {
            const float* q0 = c2w + (cl0 * E_ + i0) * OC_ + ks * 16 + hi0 * 8;
            const float* q1 = c2w + (cl0 * E_ + i1) * OC_ + ks * 16 + hi0 * 8;
            float4 u0a = *(const float4*)q0, u0b = *(const float4*)(q0 + 4);
            float4 u1a = *(const float4*)q1, u1b = *(const float4*)(q1 + 4);
            union { short8 s8; unsigned u[4]; } f;
            f.u[0] = cvtpk(fmaf(g0, u0a.x, g1 * u1a.x), fmaf(g0, u0a.y, g1 * u1a.y));
            f.u[1] = cvtpk(fmaf(g0, u0a.z, g1 * u1a.z), fmaf(g0, u0a.w, g1 * u1a.w));
            f.u[2] = cvtpk(fmaf(g0, u0b.x, g1 * u1b.x), fmaf(g0, u0b.y, g1 * u1b.y));
            f.u[3] = cvtpk(fmaf(g0, u0b.z, g1 * u1b.z), fmaf(g0, u0b.w, g1 * u1b.w));
            *(short8*)(a2L + (ks * 64 + lane) * 8) = f.s8;
        }
        if (lane == 0) {
            gF[0] = g0; gF[1] = g1;
            gI[0] = i0; gI[1] = i1;
        }
    }

    // ---- waves 4-7: write c1w -> aFl in MFMA A-fragment order ----
    if (tid >= 256) {
        const int ksoff = w_c0 >> 4;
        const int half  = (w_c0 >> 3) & 1;
        #pragma unroll
        for (int t = 0; t < 3; ++t) {
            union { short8 s8; unsigned u[4]; } w8;
            #pragma unroll
            for (int jj = 0; jj < 4; ++jj)
                w8.u[jj] = cvtpk(wv24[(2 * jj) * 3 + t], wv24[(2 * jj + 1) * 3 + t]);
            int base = ((t * 4 + ksoff) * 64 + half * 32 + w_oc) * 8;
            *(short8*)(aFl + base) = w8.s8;
        }
    }

    // ---- write tile0 -> xT0, tile1 -> xT1 ----
    #pragma unroll
    for (int jq = 0; jq < 4; ++jq) {
        float e0[4] = {A0[jq].x, A0[jq].y, A0[jq].z, A0[jq].w};
        float e1[4] = {A1[jq].x, A1[jq].y, A1[jq].z, A1[jq].w};
        float f0[4] = {B0[jq].x, B0[jq].y, B0[jq].z, B0[jq].w};
        float f1[4] = {B1[jq].x, B1[jq].y, B1[jq].z, B1[jq].w};
        #pragma unroll
        for (int r = 0; r < 4; ++r) {
            int row = jq * 64 + jb + r;
            int off = (row * 128 + c2 * 4) ^ ((row & 7) << 4);
            *(unsigned*)((char*)xT0 + off) = cvtpk(e0[r], e1[r]);
            *(unsigned*)((char*)xT1 + off) = cvtpk(f0[r], f1[r]);
        }
    }
    if (tid < 64) {
        int row = 256 + haloj;
        int off = (row * 128 + haloc * 4) ^ ((row & 7) << 4);
        *(unsigned*)((char*)xT0 + off) = cvtpk(hA0, hA1);
        *(unsigned*)((char*)xT1 + off) = cvtpk(hB0, hB1);
    }

    __syncthreads();   // the ONLY barrier

    // ---- read broadcast prep results ----
    const int cl = lane & 31;
    const int hi = lane >> 5;
    short8 a1[12];
    #pragma unroll
    for (int ks = 0; ks < 12; ++ks)
        a1[ks] = *(const short8*)(aFl + (ks * 64 + lane) * 8);
    short8 a2[2];
    a2[0] = *(const short8*)(a2L + (0 * 64 + lane) * 8);
    a2[1] = *(const short8*)(a2L + (1 * 64 + lane) * 8);
    const float g0 = gF[0], g1 = gF[1];
    const int   i0 = gI[0], i1 = gI[1];

    float* outb = out + (size_t)b * (OC_ * (size_t)LP_);

    // ---- compute both tiles (xT read-only; no further syncs) ----
    compute_tile(xT0, a1, a2, c1b, c2b, i0, i1, g0, g1, outb, S,       wv, cl, hi);
    compute_tile(xT1, a1, a2, c1b, c2b, i0, i1, g0, g1, outb, S + 256, wv, cl, hi);
}

// ---------------------------------------------------------------------------
extern "C" void kernel_launch(void* const* d_in, const int* in_sizes, int n_in,
                              void* d_out, int out_size, void* d_ws, size_t ws_size,
                              hipStream_t stream)
{
    const float* x      = (const float*)d_in[0];
    const float* w_gate = (const float*)d_in[1];
    const float* c1w    = (const float*)d_in[2];
    const float* c1b    = (const float*)d_in[3];
    const float* c2w    = (const float*)d_in[4];
    const float* c2b    = (const float*)d_in[5];
    float* out = (float*)d_out;

    fused_all<<<B_ * 8, 512, 0, stream>>>(x, w_gate, c1w, c1b, c2w, c2b, out);
}

// Round 15
// 19.164 us; speedup vs baseline: 1.0465x; 1.0157x over previous
//
#include <hip/hip_runtime.h>
#include <math.h>

// Problem constants
#define B_  32
#define D_  64
#define L_  4096
#define E_  8
#define OC_ 32
#define LP_ 4094   // L - 2 (VALID conv, kernel 3)

typedef __attribute__((ext_vector_type(8)))  short short8;
typedef __attribute__((ext_vector_type(16))) float float16;

static __device__ __forceinline__ unsigned cvtpk(float a, float b) {
    unsigned r;
    asm("v_cvt_pk_bf16_f32 %0, %1, %2" : "=v"(r) : "v"(a), "v"(b));
    return r;
}
static __device__ __forceinline__ float fast_tanh(float x) {
    float e = __expf(2.0f * x);
    return fmaf(-2.0f, __builtin_amdgcn_rcpf(e + 1.0f), 1.0f);
}

// ---------------------------------------------------------------------------
// SINGLE kernel; 2 blocks/CU for inter-block phase overlap.
// Grid 512 blocks (B x 16) x 512 threads (8 waves); block = one 256-col tile.
// LDS 47.6 KB/block -> 2 resident/CU: block A's load-wait/store-drain hides
// under block B's compute. Wave0: gates + Weff frags; waves 4-7: c1w -> LDS
// fragment staging; ONE barrier; each wave computes one 32-col MFMA tile.
// __launch_bounds__(512,4): VGPR <= 128, guarantees 2-block residency.
// ---------------------------------------------------------------------------
__global__ __launch_bounds__(512, 4)
void fused_all(const float* __restrict__ x,
               const float* __restrict__ w_gate,  // [320][8]
               const float* __restrict__ c1w,     // [32][64][3]
               const float* __restrict__ c1b,     // [32]
               const float* __restrict__ c2w,     // [256][32]
               const float* __restrict__ c2b,     // [256]
               float* __restrict__ out)           // [B][32][4094]
{
    __shared__ __align__(16) unsigned short xT[260 * 64];     // 33280 B
    __shared__ __align__(16) unsigned short aFl[12 * 64 * 8]; // 12288 B
    __shared__ __align__(16) unsigned short a2L[2 * 64 * 8];  //  2048 B
    __shared__ float gF[2];
    __shared__ int   gI[2];

    const int tid  = threadIdx.x;
    const int lane = tid & 63;
    const int wv   = tid >> 6;               // 0..7
    const int b    = blockIdx.x >> 4;
    const int l0   = (blockIdx.x & 15) << 8; // tile base 0..3840
    const float* xb = x + (size_t)b * (D_ * L_);

    // staging mapping: c2 = channel pair 0..31, jb = col offset 0..60
    const int c2 = tid >> 4;
    const int jb = (tid & 15) << 2;
    const float* p0 = xb + (size_t)(2 * c2) * L_ + l0;
    const float* p1 = p0 + L_;
    const int haloc = tid >> 1;
    const int haloj = tid & 1;

    // ---- issue x-tile loads (4 float4-pairs / thread, coalesced) ----
    float4 A0[4], A1[4];
    #pragma unroll
    for (int jq = 0; jq < 4; ++jq) {
        int j = jq * 64 + jb;
        A0[jq] = *(const float4*)(p0 + j);
        A1[jq] = *(const float4*)(p1 + j);
    }
    float hA0 = 0.f, hA1 = 0.f;
    if (tid < 64) {
        int lg = l0 + 256 + haloj;
        if (lg < L_) {                      // last tile: rows 4096/4097 dead
            hA0 = xb[(size_t)(2 * haloc) * L_ + lg];
            hA1 = xb[(size_t)(2 * haloc + 1) * L_ + lg];
        }
    }

    // ---- waves 4-7: issue c1w loads (24 consecutive floats / thread) ----
    const int tid2 = tid - 256;
    const int w_oc = tid2 >> 3;             // 0..31
    const int w_c0 = (tid2 & 7) << 3;       // 0,8,..,56
    float wv24[24];
    if (tid >= 256) {
        const float* wp = c1w + w_oc * 192 + w_c0 * 3;
        #pragma unroll
        for (int q = 0; q < 6; ++q)
            *(float4*)(wv24 + 4 * q) = *(const float4*)(wp + 4 * q);
    }

    // ---- WAVE 0: gates + conv2 Weff fragments -> LDS broadcast ----
    if (wv == 0) {
        const int d = lane;
        float part[E_];
        #pragma unroll
        for (int e = 0; e < E_; ++e) part[e] = 0.f;
        #pragma unroll
        for (int t = 0; t < 5; ++t) {
            float xvt = xb[(size_t)d * L_ + (L_ - 6) + t];
            const float* wgp = w_gate + (d * 5 + t) * E_;
            float4 wa = *(const float4*)wgp;
            float4 wb = *(const float4*)(wgp + 4);
            part[0] = fmaf(xvt, wa.x, part[0]);
            part[1] = fmaf(xvt, wa.y, part[1]);
            part[2] = fmaf(xvt, wa.z, part[2]);
            part[3] = fmaf(xvt, wa.w, part[3]);
            part[4] = fmaf(xvt, wb.x, part[4]);
            part[5] = fmaf(xvt, wb.y, part[5]);
            part[6] = fmaf(xvt, wb.z, part[6]);
            part[7] = fmaf(xvt, wb.w, part[7]);
        }
        #pragma unroll
        for (int off = 1; off < 64; off <<= 1) {
            #pragma unroll
            for (int e = 0; e < E_; ++e)
                part[e] += __shfl_xor(part[e], off, 64);
        }
        float m = part[0];
        #pragma unroll
        for (int e = 1; e < E_; ++e) m = fmaxf(m, part[e]);
        float p[E_], s = 0.f;
        #pragma unroll
        for (int e = 0; e < E_; ++e) { p[e] = expf(part[e] - m); s += p[e]; }
        float inv = 1.f / s;
        #pragma unroll
        for (int e = 0; e < E_; ++e) p[e] *= inv;

        int i0 = 0;
        #pragma unroll
        for (int e = 1; e < E_; ++e) if (p[e] > p[i0]) i0 = e;
        int i1 = (i0 == 0) ? 1 : 0;
        #pragma unroll
        for (int e = 0; e < E_; ++e) {
            if (e == i0) continue;
            if (p[e] > p[i1]) i1 = e;
        }
        const float v0 = p[i0], v1 = p[i1];
        const float den = v0 + v1 + 1e-6f;
        const float g0 = v0 / den, g1 = v1 / den;

        const int cl0 = lane & 31;
        const int hi0 = lane >> 5;
        #pragma unroll
        for (int ks = 0; ks < 2; ++ks) {
            const float* q0 = c2w + (cl0 * E_ + i0) * OC_ + ks * 16 + hi0 * 8;
            const float* q1 = c2w + (cl0 * E_ + i1) * OC_ + ks * 16 + hi0 * 8;
            float4 u0a = *(const float4*)q0, u0b = *(const float4*)(q0 + 4);
            float4 u1a = *(const float4*)q1, u1b = *(const float4*)(q1 + 4);
            union { short8 s8; unsigned u[4]; } f;
            f.u[0] = cvtpk(fmaf(g0, u0a.x, g1 * u1a.x), fmaf(g0, u0a.y, g1 * u1a.y));
            f.u[1] = cvtpk(fmaf(g0, u0a.z, g1 * u1a.z), fmaf(g0, u0a.w, g1 * u1a.w));
            f.u[2] = cvtpk(fmaf(g0, u0b.x, g1 * u1b.x), fmaf(g0, u0b.y, g1 * u1b.y));
            f.u[3] = cvtpk(fmaf(g0, u0b.z, g1 * u1b.z), fmaf(g0, u0b.w, g1 * u1b.w));
            *(short8*)(a2L + (ks * 64 + lane) * 8) = f.s8;
        }
        if (lane == 0) {
            gF[0] = g0; gF[1] = g1;
            gI[0] = i0; gI[1] = i1;
        }
    }

    // ---- waves 4-7: write c1w -> aFl in MFMA A-fragment order ----
    if (tid >= 256) {
        const int ksoff = w_c0 >> 4;
        const int half  = (w_c0 >> 3) & 1;
        #pragma unroll
        for (int t = 0; t < 3; ++t) {
            union { short8 s8; unsigned u[4]; } w8;
            #pragma unroll
            for (int jj = 0; jj < 4; ++jj)
                w8.u[jj] = cvtpk(wv24[(2 * jj) * 3 + t], wv24[(2 * jj + 1) * 3 + t]);
            int base = ((t * 4 + ksoff) * 64 + half * 32 + w_oc) * 8;
            *(short8*)(aFl + base) = w8.s8;
        }
    }

    // ---- write x tile -> xT (XOR-swizzled) ----
    #pragma unroll
    for (int jq = 0; jq < 4; ++jq) {
        float e0[4] = {A0[jq].x, A0[jq].y, A0[jq].z, A0[jq].w};
        float e1[4] = {A1[jq].x, A1[jq].y, A1[jq].z, A1[jq].w};
        #pragma unroll
        for (int r = 0; r < 4; ++r) {
            int row = jq * 64 + jb + r;
            int off = (row * 128 + c2 * 4) ^ ((row & 7) << 4);
            *(unsigned*)((char*)xT + off) = cvtpk(e0[r], e1[r]);
        }
    }
    if (tid < 64) {
        int row = 256 + haloj;
        int off = (row * 128 + haloc * 4) ^ ((row & 7) << 4);
        *(unsigned*)((char*)xT + off) = cvtpk(hA0, hA1);
    }

    __syncthreads();   // the ONLY barrier

    // ---- read broadcast prep results ----
    const int cl = lane & 31;
    const int hi = lane >> 5;
    short8 a1[12];
    #pragma unroll
    for (int ks = 0; ks < 12; ++ks)
        a1[ks] = *(const short8*)(aFl + (ks * 64 + lane) * 8);
    short8 a2[2];
    a2[0] = *(const short8*)(a2L + (0 * 64 + lane) * 8);
    a2[1] = *(const short8*)(a2L + (1 * 64 + lane) * 8);
    const float g0 = gF[0], g1 = gF[1];
    const int   i0 = gI[0], i1 = gI[1];

    // ---- conv1: 12 x mfma_32x32x16_bf16 (wave's 32-col group) ----
    const int cb = wv * 32;
    float16 acc = (float16)0.0f;
    #pragma unroll
    for (int t = 0; t < 3; ++t) {
        int row = cb + cl + t;
        int rb  = row * 128;
        int swz = (row & 7) << 4;
        #pragma unroll
        for (int q = 0; q < 4; ++q) {
            int off = (rb + q * 32 + hi * 16) ^ swz;
            short8 bf = *(const short8*)((const char*)xT + off);
            acc = __builtin_amdgcn_mfma_f32_32x32x16_bf16(a1[t * 4 + q], bf, acc, 0, 0, 0);
        }
    }

    // ---- bias + fast tanh ----
    float th[16];
    #pragma unroll
    for (int r = 0; r < 16; ++r) {
        int row = (r & 3) + 8 * (r >> 2) + 4 * hi;
        th[r] = fast_tanh(acc[r] + c1b[row]);
    }

    // ---- conv2 B-frags in-register via half-wave swap (lane ^ 32) ----
    unsigned x0a = hi ? cvtpk(th[0],  th[1])  : cvtpk(th[4],  th[5]);
    unsigned x0b = hi ? cvtpk(th[2],  th[3])  : cvtpk(th[6],  th[7]);
    unsigned x1a = hi ? cvtpk(th[8],  th[9])  : cvtpk(th[12], th[13]);
    unsigned x1b = hi ? cvtpk(th[10], th[11]) : cvtpk(th[14], th[15]);
    unsigned r0a = (unsigned)__shfl_xor((int)x0a, 32, 64);
    unsigned r0b = (unsigned)__shfl_xor((int)x0b, 32, 64);
    unsigned r1a = (unsigned)__shfl_xor((int)x1a, 32, 64);
    unsigned r1b = (unsigned)__shfl_xor((int)x1b, 32, 64);

    union U { short8 s8; unsigned u[4]; };
    U b0, b1;
    b0.u[0] = hi ? r0a : cvtpk(th[0], th[1]);
    b0.u[1] = hi ? r0b : cvtpk(th[2], th[3]);
    b0.u[2] = hi ? cvtpk(th[4], th[5]) : r0a;
    b0.u[3] = hi ? cvtpk(th[6], th[7]) : r0b;
    b1.u[0] = hi ? r1a : cvtpk(th[8], th[9]);
    b1.u[1] = hi ? r1b : cvtpk(th[10], th[11]);
    b1.u[2] = hi ? cvtpk(th[12], th[13]) : r1a;
    b1.u[3] = hi ? cvtpk(th[14], th[15]) : r1b;

    float16 acc2 = (float16)0.0f;
    acc2 = __builtin_amdgcn_mfma_f32_32x32x16_bf16(a2[0], b0.s8, acc2, 0, 0, 0);
    acc2 = __builtin_amdgcn_mfma_f32_32x32x16_bf16(a2[1], b1.s8, acc2, 0, 0, 0);

    // ---- direct stores; bias2 from L1-hot c2b ----
    int l = l0 + cb + cl;
    if (l < LP_) {
        float* ob = out + (size_t)b * (OC_ * (size_t)LP_) + l;
        #pragma unroll
        for (int r = 0; r < 16; ++r) {
            int row = (r & 3) + 8 * (r >> 2) + 4 * hi;
            float bb = fmaf(g0, c2b[row * E_ + i0], g1 * c2b[row * E_ + i1]);
            ob[(size_t)row * LP_] = acc2[r] + bb;
        }
    }
}

// ---------------------------------------------------------------------------
extern "C" void kernel_launch(void* const* d_in, const int* in_sizes, int n_in,
                              void* d_out, int out_size, void* d_ws, size_t ws_size,
                              hipStream_t stream)
{
    const float* x      = (const float*)d_in[0];
    const float* w_gate = (const float*)d_in[1];
    const float* c1w    = (const float*)d_in[2];
    const float* c1b    = (const float*)d_in[3];
    const float* c2w    = (const float*)d_in[4];
    const float* c2b    = (const float*)d_in[5];
    float* out = (float*)d_out;

    fused_all<<<B_ * 16, 512, 0, stream>>>(x, w_gate, c1w, c1b, c2w, c2b, out);
}